// Round 3
// baseline (793.236 us; speedup 1.0000x reference)
//
#include <hip/hip_runtime.h>

// ColorQuantizer: out[b,c,h,w] = palette[argmin_i dist(processed(x[b,:,h,w]), palette_i)][c]
// processed = relu(x@W1 + b1) @ W2 + b2   (fp32, replicate reference op order)
//
// R3: sq-space argmin (sqrt is monotone); rare near-tie lanes take an INLINED
// exact-sqrt fallback (R2's noinline call caused a caller-save spill storm:
// VGPR 256, +860MB scratch traffic). Guard: final pv == min sq over indices
// earlier than the winner; fallback iff pv <= bd*(1+2^-18) (sqrt collision
// window is ~2^-23 rel). Bit-identical output to the exact kernel (absmax 0.0
// in R1 and R2). Arithmetic packed as float2 -> v_pk_fma_f32 where possible.

typedef float v2f __attribute__((ext_vector_type(2)));

static __device__ __forceinline__ v2f v2(float a){ v2f r; r.x=a; r.y=a; return r; }
static __device__ __forceinline__ v2f fma2(v2f a, v2f b, v2f c){ return __builtin_elementwise_fma(a,b,c); }
static __device__ __forceinline__ v2f max2(v2f a, v2f b){ return __builtin_elementwise_max(a,b); }

#define PV(v) ((float)(v)/255.0f*2.0f-1.0f)
#define ROWF(r,g,c) {PV(r), PV(g), PV(c)}

// Runtime-indexed palette table for the final gather (VMEM; mem pipe is idle).
__device__ const float PALG[16][3] = {
  ROWF(0,0,0),       ROWF(255,255,255), ROWF(255,0,0),     ROWF(0,255,0),
  ROWF(0,0,255),     ROWF(255,255,0),   ROWF(255,0,255),   ROWF(0,255,255),
  ROWF(128,128,128), ROWF(128,0,0),     ROWF(0,128,0),     ROWF(0,0,128),
  ROWF(128,128,0),   ROWF(128,0,128),   ROWF(0,128,128),   ROWF(192,192,192)
};

// Compile-time palette for the unrolled loops (folds to immediates).
constexpr int COLI[16][3] = {
  {0,0,0},{255,255,255},{255,0,0},{0,255,0},{0,0,255},{255,255,0},
  {255,0,255},{0,255,255},{128,128,128},{128,0,0},{0,128,0},{0,0,128},
  {128,128,0},{128,0,128},{0,128,128},{192,192,192}
};
constexpr float PVF(int v){ return (float)v/255.0f*2.0f-1.0f; }
constexpr float PXc(int i){ return PVF(COLI[i][0]); }
constexpr float PYc(int i){ return PVF(COLI[i][1]); }
constexpr float PZc(int i){ return PVF(COLI[i][2]); }
// sum(PALETTE*PALETTE, axis=-1) with the reference's reduce order
constexpr float PSQc(int i){ return (PXc(i)*PXc(i) + PYc(i)*PYc(i)) + PZc(i)*PZc(i); }

constexpr int HW    = 512*512;
constexpr int PXT   = 8;          // pixels per thread (4 float2 pairs)
constexpr int BLOCK = 256;

// R1's exact path (bit-matched numpy: absmax 0.0). Inlined under a rare
// branch -- no call ABI, cold code skipped via exec-mask branch.
static __device__ __forceinline__ int slow_argmin(float p0, float p1, float p2, float psq)
{
#pragma clang fp contract(off)
    float bd = 3.4e38f;
    int   bi = 0;
#pragma unroll
    for (int i = 0; i < 16; ++i) {
        float dot = __builtin_fmaf(p2, PZc(i), __builtin_fmaf(p1, PYc(i), p0*PXc(i)));
        float sq  = (psq - 2.0f*dot) + PSQc(i);
        float d   = sqrtf(fmaxf(sq, 0.0f));
        if (d < bd) { bd = d; bi = i; }
    }
    return bi;
}

__global__ __launch_bounds__(BLOCK) void cq_kernel(
    const float* __restrict__ x,   const float* __restrict__ W1g,
    const float* __restrict__ b1g, const float* __restrict__ W2g,
    const float* __restrict__ b2g, float* __restrict__ out)
{
#pragma clang fp contract(off)
    __shared__ float sW1[96];  // W1[3][32] row-major
    __shared__ float sb1[32];
    __shared__ float sW2[96];  // W2[32][3] row-major
    __shared__ float sb2[3];

    const int t = threadIdx.x;
    if      (t < 96)  sW1[t]       = W1g[t];
    else if (t < 128) sb1[t-96]    = b1g[t-96];
    else if (t < 224) sW2[t-128]   = W2g[t-128];
    else if (t < 227) sb2[t-224]   = b2g[t-224];
    __syncthreads();

    const int pix = (blockIdx.x * BLOCK + t) * PXT;
    const int img = pix >> 18;                       // HW = 2^18
    const int hw  = pix & (HW - 1);
    const size_t base = (size_t)img * (size_t)(3*HW) + (size_t)hw;

    v2f X0[4], X1[4], X2[4];
    {
        float4 a0 = *(const float4*)(x + base);
        float4 a1 = *(const float4*)(x + base + 4);
        float4 c0 = *(const float4*)(x + base + HW);
        float4 c1 = *(const float4*)(x + base + HW + 4);
        float4 e0 = *(const float4*)(x + base + 2*HW);
        float4 e1 = *(const float4*)(x + base + 2*HW + 4);
        X0[0].x=a0.x; X0[0].y=a0.y; X0[1].x=a0.z; X0[1].y=a0.w;
        X0[2].x=a1.x; X0[2].y=a1.y; X0[3].x=a1.z; X0[3].y=a1.w;
        X1[0].x=c0.x; X1[0].y=c0.y; X1[1].x=c0.z; X1[1].y=c0.w;
        X1[2].x=c1.x; X1[2].y=c1.y; X1[3].x=c1.z; X1[3].y=c1.w;
        X2[0].x=e0.x; X2[0].y=e0.y; X2[1].x=e0.z; X2[1].y=e0.w;
        X2[2].x=e1.x; X2[2].y=e1.y; X2[3].x=e1.z; X2[3].y=e1.w;
    }

    v2f P0[4], P1[4], P2[4];
#pragma unroll
    for (int pp = 0; pp < 4; ++pp) { P0[pp]=v2(0.f); P1[pp]=v2(0.f); P2[pp]=v2(0.f); }

    // Fused MLP (packed pairs): h = relu(fma(x2,w2,fma(x1,w1,x0*w0)) + b1_j)
#pragma unroll
    for (int j = 0; j < 32; ++j) {
        const v2f w0 = v2(sW1[j]), w1 = v2(sW1[32+j]), w2 = v2(sW1[64+j]);
        const v2f bb = v2(sb1[j]);
        const v2f u0 = v2(sW2[3*j]), u1 = v2(sW2[3*j+1]), u2 = v2(sW2[3*j+2]);
#pragma unroll
        for (int pp = 0; pp < 4; ++pp) {
            v2f h = fma2(X2[pp], w2, fma2(X1[pp], w1, X0[pp]*w0));
            h = h + bb;
            h = max2(h, v2(0.0f));
            P0[pp] = fma2(h, u0, P0[pp]);
            P1[pp] = fma2(h, u1, P1[pp]);
            P2[pp] = fma2(h, u2, P2[pp]);
        }
    }

    const v2f bz0 = v2(sb2[0]), bz1 = v2(sb2[1]), bz2 = v2(sb2[2]);

    int best[PXT];
#pragma unroll
    for (int pp = 0; pp < 4; ++pp) {
        const v2f p0 = P0[pp] + bz0;
        const v2f p1 = P1[pp] + bz1;
        const v2f p2 = P2[pp] + bz2;
        const v2f psq = (p0*p0 + p1*p1) + p2*p2;   // reference reduce order

        float bd0 = 3.4e38f, bd1 = 3.4e38f;        // running min of clamped sq
        float pv0 = 3.4e38f, pv1 = 3.4e38f;        // min over indices BEFORE current best
        int   bi0 = 0,       bi1 = 0;
#pragma unroll
        for (int i = 0; i < 16; ++i) {
            v2f dot = fma2(p2, v2(PZc(i)), fma2(p1, v2(PYc(i)), p0*v2(PXc(i))));
            v2f sq  = (psq - v2(2.0f)*dot) + v2(PSQc(i));   // same assoc as reference
            sq = max2(sq, v2(0.0f));                        // ref clamps before sqrt
            bool c0 = sq.x < bd0;
            pv0 = c0 ? bd0 : pv0;  bd0 = c0 ? sq.x : bd0;  bi0 = c0 ? i : bi0;
            bool c1 = sq.y < bd1;
            pv1 = c1 ? bd1 : pv1;  bd1 = c1 ? sq.y : bd1;  bi1 = c1 ? i : bi1;
        }
        // Ambiguous iff an EARLIER index is within rel 2^-18 of the min
        // (sqrt collision window is ~2^-23; 16x margin). Rare -> inlined exact path.
        if (__builtin_expect(pv0 <= bd0 * 1.000004f, 0))
            bi0 = slow_argmin(p0.x, p1.x, p2.x, psq.x);
        if (__builtin_expect(pv1 <= bd1 * 1.000004f, 0))
            bi1 = slow_argmin(p0.y, p1.y, p2.y, psq.y);
        best[2*pp]   = bi0;
        best[2*pp+1] = bi1;
    }

    float* op = out + base;   // output shares the [b][c][hw] layout
    float4 o;
    o = make_float4(PALG[best[0]][0], PALG[best[1]][0], PALG[best[2]][0], PALG[best[3]][0]);
    *(float4*)(op) = o;
    o = make_float4(PALG[best[4]][0], PALG[best[5]][0], PALG[best[6]][0], PALG[best[7]][0]);
    *(float4*)(op + 4) = o;
    o = make_float4(PALG[best[0]][1], PALG[best[1]][1], PALG[best[2]][1], PALG[best[3]][1]);
    *(float4*)(op + HW) = o;
    o = make_float4(PALG[best[4]][1], PALG[best[5]][1], PALG[best[6]][1], PALG[best[7]][1]);
    *(float4*)(op + HW + 4) = o;
    o = make_float4(PALG[best[0]][2], PALG[best[1]][2], PALG[best[2]][2], PALG[best[3]][2]);
    *(float4*)(op + 2*HW) = o;
    o = make_float4(PALG[best[4]][2], PALG[best[5]][2], PALG[best[6]][2], PALG[best[7]][2]);
    *(float4*)(op + 2*HW + 4) = o;
}

extern "C" void kernel_launch(void* const* d_in, const int* in_sizes, int n_in,
                              void* d_out, int out_size, void* d_ws, size_t ws_size,
                              hipStream_t stream) {
    const float* x  = (const float*)d_in[0];
    const float* W1 = (const float*)d_in[1];
    const float* b1 = (const float*)d_in[2];
    const float* W2 = (const float*)d_in[3];
    const float* b2 = (const float*)d_in[4];
    float* outp = (float*)d_out;

    constexpr int NPIX = 32 * HW;                    // 8,388,608
    constexpr int GRID = NPIX / (BLOCK * PXT);       // 4096 blocks, exact
    hipLaunchKernelGGL(cq_kernel, dim3(GRID), dim3(BLOCK), 0, stream,
                       x, W1, b1, W2, b2, outp);
}

// Round 4
// 275.534 us; speedup vs baseline: 2.8789x; 2.8789x over previous
//
#include <hip/hip_runtime.h>

// ColorQuantizer: out[b,c,h,w] = palette[argmin_i dist(processed(x[b,:,h,w]), palette_i)][c]
// processed = relu(x@W1 + b1) @ W2 + b2   (fp32, replicate reference op order)
//
// R4: R1's known-good scalar structure (112 VGPR, 95% VALU), minus the 16
// per-pixel sqrts. Hot loop tracks (min, second-min, argmin) of clamped sq.
// sqrt is monotone, so argmin(sq) == argmin(d) unless two sq round to the
// same d. Resolution ladder:
//   (a) prefilter: pv <= bd*(1+4e-6)  [sqrt collision window is ~2.4e-7 rel]
//   (b) 2 sqrts: if sqrtf(pv) != sqrtf(bd), no d-tie exists (sandwich arg)
//   (c) true d-tie only (~0-5 px/image): ROLLED exact R1 sqrt rescan
// (R2/R3 lesson: the unrolled-inline fallback + v2f state spilled to scratch
// -> VGPR 256, +1.1GB HBM traffic. Keep scalar, keep cold code rolled.)

#define PV(v) ((float)(v)/255.0f*2.0f-1.0f)
#define ROWF(r,g,c) {PV(r), PV(g), PV(c)}

// Runtime-indexed palette (global .rodata): epilogue gather + cold rescan.
__device__ const float PALG[16][3] = {
  ROWF(0,0,0),       ROWF(255,255,255), ROWF(255,0,0),     ROWF(0,255,0),
  ROWF(0,0,255),     ROWF(255,255,0),   ROWF(255,0,255),   ROWF(0,255,255),
  ROWF(128,128,128), ROWF(128,0,0),     ROWF(0,128,0),     ROWF(0,0,128),
  ROWF(128,128,0),   ROWF(128,0,128),   ROWF(0,128,128),   ROWF(192,192,192)
};

// Compile-time palette for the hot unrolled loop (folds to immediates).
constexpr int COLI[16][3] = {
  {0,0,0},{255,255,255},{255,0,0},{0,255,0},{0,0,255},{255,255,0},
  {255,0,255},{0,255,255},{128,128,128},{128,0,0},{0,128,0},{0,0,128},
  {128,128,0},{128,0,128},{0,128,128},{192,192,192}
};
constexpr float PVF(int v){ return (float)v/255.0f*2.0f-1.0f; }
constexpr float PXc(int i){ return PVF(COLI[i][0]); }
constexpr float PYc(int i){ return PVF(COLI[i][1]); }
constexpr float PZc(int i){ return PVF(COLI[i][2]); }
// sum(PALETTE*PALETTE, axis=-1), reference reduce order: (x*x + y*y) + z*z
constexpr float PSQc(int i){ return (PXc(i)*PXc(i) + PYc(i)*PYc(i)) + PZc(i)*PZc(i); }

constexpr int HW    = 512*512;
constexpr int PXT   = 8;          // pixels per thread
constexpr int BLOCK = 256;

// Cold path: R1's exact sqrt argmin, ROLLED, palette from memory.
// Executed only on true d-ties (expected handful of pixels per image).
static __device__ __forceinline__ int exact_rescan(float p0, float p1, float p2, float psq)
{
#pragma clang fp contract(off)
    float bd = 3.4e38f;
    int   bi = 0;
#pragma unroll 1
    for (int i = 0; i < 16; ++i) {
        const float cx = PALG[i][0], cy = PALG[i][1], cz = PALG[i][2];
        const float csq = (cx*cx + cy*cy) + cz*cz;          // == PSQc(i) bitwise
        float dot = __builtin_fmaf(p2, cz, __builtin_fmaf(p1, cy, p0*cx));
        float sq  = (psq - 2.0f*dot) + csq;
        float d   = sqrtf(fmaxf(sq, 0.0f));
        if (d < bd) { bd = d; bi = i; }
    }
    return bi;
}

__global__ __launch_bounds__(BLOCK) void cq_kernel(
    const float* __restrict__ x,   const float* __restrict__ W1g,
    const float* __restrict__ b1g, const float* __restrict__ W2g,
    const float* __restrict__ b2g, float* __restrict__ out)
{
#pragma clang fp contract(off)
    __shared__ float sW1[96];  // W1[3][32] row-major
    __shared__ float sb1[32];
    __shared__ float sW2[96];  // W2[32][3] row-major
    __shared__ float sb2[3];

    const int t = threadIdx.x;
    if      (t < 96)  sW1[t]       = W1g[t];
    else if (t < 128) sb1[t-96]    = b1g[t-96];
    else if (t < 224) sW2[t-128]   = W2g[t-128];
    else if (t < 227) sb2[t-224]   = b2g[t-224];
    __syncthreads();

    const int pix = (blockIdx.x * BLOCK + t) * PXT;
    const int img = pix >> 18;                       // HW = 2^18
    const int hw  = pix & (HW - 1);
    const size_t base = (size_t)img * (size_t)(3*HW) + (size_t)hw;

    float X0[PXT], X1[PXT], X2[PXT];
    {
        float4 a0 = *(const float4*)(x + base);
        float4 a1 = *(const float4*)(x + base + 4);
        float4 c0 = *(const float4*)(x + base + HW);
        float4 c1 = *(const float4*)(x + base + HW + 4);
        float4 e0 = *(const float4*)(x + base + 2*HW);
        float4 e1 = *(const float4*)(x + base + 2*HW + 4);
        X0[0]=a0.x; X0[1]=a0.y; X0[2]=a0.z; X0[3]=a0.w;
        X0[4]=a1.x; X0[5]=a1.y; X0[6]=a1.z; X0[7]=a1.w;
        X1[0]=c0.x; X1[1]=c0.y; X1[2]=c0.z; X1[3]=c0.w;
        X1[4]=c1.x; X1[5]=c1.y; X1[6]=c1.z; X1[7]=c1.w;
        X2[0]=e0.x; X2[1]=e0.y; X2[2]=e0.z; X2[3]=e0.w;
        X2[4]=e1.x; X2[5]=e1.y; X2[6]=e1.z; X2[7]=e1.w;
    }

    float P0[PXT], P1[PXT], P2[PXT];
#pragma unroll
    for (int k = 0; k < PXT; ++k) { P0[k]=0.0f; P1[k]=0.0f; P2[k]=0.0f; }

    // Fused MLP: h = relu(fma(x2,w2,fma(x1,w1,x0*w0)) + b1_j); P_c += h*W2[j][c]
#pragma unroll
    for (int j = 0; j < 32; ++j) {
        const float w0 = sW1[j], w1 = sW1[32+j], w2 = sW1[64+j];
        const float bb = sb1[j];
        const float u0 = sW2[3*j], u1 = sW2[3*j+1], u2 = sW2[3*j+2];
#pragma unroll
        for (int k = 0; k < PXT; ++k) {
            float h = __builtin_fmaf(X2[k], w2, __builtin_fmaf(X1[k], w1, X0[k]*w0));
            h = h + bb;
            h = fmaxf(h, 0.0f);
            P0[k] = __builtin_fmaf(h, u0, P0[k]);
            P1[k] = __builtin_fmaf(h, u1, P1[k]);
            P2[k] = __builtin_fmaf(h, u2, P2[k]);
        }
    }

    int best[PXT];
#pragma unroll
    for (int k = 0; k < PXT; ++k) {
        const float p0 = P0[k] + sb2[0];
        const float p1 = P1[k] + sb2[1];
        const float p2 = P2[k] + sb2[2];
        const float psq = (p0*p0 + p1*p1) + p2*p2;   // reference reduce order

        float bd = 3.4e38f;     // min clamped sq
        float pv = 3.4e38f;     // second-min clamped sq (any index)
        int   bi = 0;
#pragma unroll
        for (int i = 0; i < 16; ++i) {
            float dot = __builtin_fmaf(p2, PZc(i), __builtin_fmaf(p1, PYc(i), p0*PXc(i)));
            // 2*dot is exact (pow2 scale), so fma(dot,-2,psq) == (psq - 2.0f*dot) bitwise
            float sq  = __builtin_fmaf(dot, -2.0f, psq) + PSQc(i);
            sq = fmaxf(sq, 0.0f);                    // ref clamps before sqrt
            bool c = sq < bd;                        // strict: first occurrence wins
            float m = fminf(sq, pv);
            pv = c ? bd : m;
            bi = c ? i  : bi;
            bd = c ? sq : bd;
        }
        // d-tie possible only if pv within sqrt's rounding-collision window of bd.
        if (__builtin_expect(pv <= bd * 1.000004f, 0)) {
            // 2 sqrts decide: if they differ, no candidate shares d with bd
            // (bd <= pv <= any other sq; sqrt monotone => sandwiched).
            if (sqrtf(pv) == sqrtf(bd))
                bi = exact_rescan(p0, p1, p2, psq);
        }
        best[k] = bi;
    }

    float* op = out + base;   // output shares the [b][c][hw] layout
    float4 o;
    o = make_float4(PALG[best[0]][0], PALG[best[1]][0], PALG[best[2]][0], PALG[best[3]][0]);
    *(float4*)(op) = o;
    o = make_float4(PALG[best[4]][0], PALG[best[5]][0], PALG[best[6]][0], PALG[best[7]][0]);
    *(float4*)(op + 4) = o;
    o = make_float4(PALG[best[0]][1], PALG[best[1]][1], PALG[best[2]][1], PALG[best[3]][1]);
    *(float4*)(op + HW) = o;
    o = make_float4(PALG[best[4]][1], PALG[best[5]][1], PALG[best[6]][1], PALG[best[7]][1]);
    *(float4*)(op + HW + 4) = o;
    o = make_float4(PALG[best[0]][2], PALG[best[1]][2], PALG[best[2]][2], PALG[best[3]][2]);
    *(float4*)(op + 2*HW) = o;
    o = make_float4(PALG[best[4]][2], PALG[best[5]][2], PALG[best[6]][2], PALG[best[7]][2]);
    *(float4*)(op + 2*HW + 4) = o;
}

extern "C" void kernel_launch(void* const* d_in, const int* in_sizes, int n_in,
                              void* d_out, int out_size, void* d_ws, size_t ws_size,
                              hipStream_t stream) {
    const float* x  = (const float*)d_in[0];
    const float* W1 = (const float*)d_in[1];
    const float* b1 = (const float*)d_in[2];
    const float* W2 = (const float*)d_in[3];
    const float* b2 = (const float*)d_in[4];
    float* outp = (float*)d_out;

    constexpr int NPIX = 32 * HW;                    // 8,388,608
    constexpr int GRID = NPIX / (BLOCK * PXT);       // 4096 blocks, exact
    hipLaunchKernelGGL(cq_kernel, dim3(GRID), dim3(BLOCK), 0, stream,
                       x, W1, b1, W2, b2, outp);
}